// Round 5
// baseline (380.320 us; speedup 1.0000x reference)
//
#include <hip/hip_runtime.h>

// GraphSAGE 3-layer, N=50000, E=1.6M, D=128.
// R10: register-tiled dual_gemm — 4 row-tiles (64 rows) per wave, each packed
//      weight fragment loaded ONCE and reused by 24 MFMAs (4 tiles x 6
//      products). Cuts per-dispatch weight reads 400MB -> 100MB (the gemm was
//      weight-load-bound; L1=32KB can't hold the 128KB working set).
//      agg_add / CSR build unchanged from R9 (agg is at the random-granule
//      L2-miss path ceiling ~3.6TB/s; phasing attempts R7/R9 both failed).

constexpr int N_NODES = 50000;
constexpr int N_EDGES = 1600000;
constexpr int D = 128;
constexpr int NTILES = N_NODES / 16;          // 3125

constexpr int NBUCK = 392;                    // ceil(50176/128) node-range buckets
constexpr int BCAP  = 6144;                   // capacity per bucket (mean 4082)
constexpr int EPB   = 4096;                   // edges per block in count/scatter
constexpr int CS_BLOCKS = (N_EDGES + EPB - 1) / EPB;   // 391
constexpr int GC_STRIDE = 16;                 // 64B pad: 1 atomic counter per sector

constexpr int NT  = 8;                        // src tiles (8192 nodes each)
constexpr int TSH = 13;                       // tile = src >> 13

typedef __bf16 bf16x8 __attribute__((ext_vector_type(8)));
typedef float f32x4 __attribute__((ext_vector_type(4)));
union U8 { bf16x8 v; __bf16 e[8]; };

// ---------------- zero ----------------------------------------------------
__global__ void zero1(int* __restrict__ a, int n) {
    int i = blockIdx.x * blockDim.x + threadIdx.x;
    if (i < n) a[i] = 0;
}

// ---------------- bucket count + scatter ----------------------------------
// Per block: LDS hist over 392 buckets (dst>>7), reserve space per bucket with
// ONE padded global atomic, then write packed (dstlow<<16 | src) to bucketbuf.
__global__ __launch_bounds__(256) void bucket_count_scatter(
        const int* __restrict__ dst, const int* __restrict__ src,
        int* __restrict__ gcursor, int* __restrict__ bucketbuf) {
    __shared__ int hcnt[NBUCK];
    __shared__ int hbase[NBUCK];
    const int tid = threadIdx.x;
    for (int i = tid; i < NBUCK; i += 256) hcnt[i] = 0;
    __syncthreads();

    const int e0 = blockIdx.x * EPB;
    int d[16], lp[16];
    #pragma unroll
    for (int t = 0; t < 16; ++t) {
        const int e = e0 + t * 256 + tid;
        if (e < N_EDGES) {
            d[t] = dst[e];
            lp[t] = atomicAdd(&hcnt[d[t] >> 7], 1);   // LDS atomic, local pos
        } else {
            d[t] = 0; lp[t] = -1;
        }
    }
    __syncthreads();

    for (int i = tid; i < NBUCK; i += 256) {
        const int c = hcnt[i];
        hbase[i] = c ? atomicAdd(&gcursor[i * GC_STRIDE], c) : 0;  // 1/(blk,bucket)
    }
    __syncthreads();

    #pragma unroll
    for (int t = 0; t < 16; ++t) {
        const int e = e0 + t * 256 + tid;
        if (e < N_EDGES) {
            const int s  = src[e];
            const int bk = d[t] >> 7;
            const int p  = hbase[bk] + lp[t];
            if (p < BCAP)
                bucketbuf[bk * BCAP + p] = ((d[t] & 127) << 16) | s;
        }
    }
}

// ---------------- scan bucket totals -> bases ------------------------------
__global__ void bucket_scan(const int* __restrict__ gcursor,
                            int* __restrict__ bucket_base) {
    __shared__ int wsum[8], wpre[8];
    const int t = threadIdx.x;                // 512 threads, 8 waves
    const int lane = t & 63, w = t >> 6;
    int v = 0;
    if (t < NBUCK) { v = gcursor[t * GC_STRIDE]; if (v > BCAP) v = BCAP; }
    int x = v;
    #pragma unroll
    for (int off = 1; off < 64; off <<= 1) {
        int tt = __shfl_up(x, off, 64);
        if (lane >= off) x += tt;
    }
    if (lane == 63) wsum[w] = x;
    __syncthreads();
    if (t < 8) {
        int s = wsum[t], y = s;
        #pragma unroll
        for (int off = 1; off < 8; off <<= 1) {
            int tt = __shfl_up(y, off, 64);
            if (t >= off) y += tt;
        }
        wpre[t] = y - s;
    }
    __syncthreads();
    if (t < NBUCK) bucket_base[t] = wpre[w] + (x - v);
}

// ---------------- per-bucket CSR finalize (tile-sorted, NT=8) --------------
// One block per bucket: LDS hist of 128 nodes x 8 src-tiles -> global offsets
// tp[node*8+t] + inv_deg, then LDS-cursor scatter of esrc grouped by
// (node, tile). Result: esrc globally sorted by (dst, src>>13).
__global__ __launch_bounds__(256) void bucket_csr(
        const int* __restrict__ gcursor, const int* __restrict__ bucket_base,
        const int* __restrict__ bucketbuf, int* __restrict__ tp,
        float* __restrict__ inv_deg, int* __restrict__ esrc) {
    __shared__ int h[1024];
    __shared__ int cur[1024];
    __shared__ int wsum[4], wpre[4];
    const int bk = blockIdx.x, tid = threadIdx.x;
    int cnt = gcursor[bk * GC_STRIDE];
    if (cnt > BCAP) cnt = BCAP;
    const int base = bucket_base[bk];
    #pragma unroll
    for (int k = 0; k < 4; ++k) h[tid * 4 + k] = 0;
    __syncthreads();

    const int* bb = bucketbuf + (size_t)bk * BCAP;
    for (int i = tid; i < cnt; i += 256) {
        const int p = bb[i];
        atomicAdd(&h[((p >> 16) << 3) | ((p & 0xFFFF) >> TSH)], 1);
    }
    __syncthreads();

    if (tid < 128) {
        int dg = 0;
        #pragma unroll
        for (int k = 0; k < 8; ++k) dg += h[tid * 8 + k];
        inv_deg[bk * 128 + tid] = 1.0f / fmaxf((float)dg, 1.0f);
    }

    // exclusive scan of 1024 counters (4 per thread)
    const int v0 = h[tid * 4], v1 = h[tid * 4 + 1];
    const int v2 = h[tid * 4 + 2], v3 = h[tid * 4 + 3];
    const int s = v0 + v1 + v2 + v3;
    int x = s;
    const int lane = tid & 63, w = tid >> 6;
    #pragma unroll
    for (int off = 1; off < 64; off <<= 1) {
        int tt = __shfl_up(x, off, 64);
        if (lane >= off) x += tt;
    }
    if (lane == 63) wsum[w] = x;
    __syncthreads();
    if (tid == 0) {
        int a = 0;
        #pragma unroll
        for (int k = 0; k < 4; ++k) { wpre[k] = a; a += wsum[k]; }
    }
    __syncthreads();
    const int e0 = wpre[w] + (x - s);
    const int e1 = e0 + v0, e2 = e1 + v1, e3 = e2 + v2;
    cur[tid * 4] = e0; cur[tid * 4 + 1] = e1;
    cur[tid * 4 + 2] = e2; cur[tid * 4 + 3] = e3;
    int* tpo = tp + (size_t)bk * 1024 + tid * 4;
    tpo[0] = base + e0; tpo[1] = base + e1; tpo[2] = base + e2; tpo[3] = base + e3;
    __syncthreads();

    for (int i = tid; i < cnt; i += 256) {
        const int p = bb[i];
        const int f = ((p >> 16) << 3) | ((p & 0xFFFF) >> TSH);
        esrc[base + atomicAdd(&cur[f], 1)] = p & 0xFFFF;
    }
}

// ---------------- pack W into MFMA B-fragment order, hi+lo ---------------
__global__ void pack_w(const float* __restrict__ w0, const float* __restrict__ w1,
                       const float* __restrict__ w2, const float* __restrict__ w3,
                       const float* __restrict__ w4, const float* __restrict__ w5,
                       __bf16* __restrict__ outbase) {
    const float* ws[6] = {w0, w1, w2, w3, w4, w5};
    const float* W = ws[blockIdx.y];
    __bf16* o = outbase + (size_t)blockIdx.y * 32768;
    int idx = blockIdx.x * 256 + threadIdx.x;   // 0..16383
    int t = idx & 7;
    int lane = (idx >> 3) & 63;
    int ks = (idx >> 9) & 3;
    int jt = idx >> 11;
    int j = jt * 16 + (lane & 15);
    int k = ks * 32 + (lane >> 4) * 8 + t;
    float w = W[j * D + k];
    __bf16 hi = (__bf16)w;
    o[idx] = hi;
    o[16384 + idx] = (__bf16)(w - (float)hi);
}

// ---------------- dual GEMM: y = h@Ws^T + b (fp32), z = h@Wn^T (bf16) ----
// R10: 4 row-tiles (64 rows) per wave; each weight fragment loaded once and
// reused by 4 tiles x 6 MFMA. Numerics identical to R5's 1-tile version.
__global__ __launch_bounds__(256) void dual_gemm(
        const float* __restrict__ h, const __bf16* __restrict__ Bs,
        const __bf16* __restrict__ Bn, const float* __restrict__ bias,
        float* __restrict__ y_self, __bf16* __restrict__ z) {
    const int wave = threadIdx.x >> 6;
    const int lane = threadIdx.x & 63;
    const int t0 = (blockIdx.x * 4 + wave) * 4;     // first of 4 tiles
    if (t0 >= NTILES) return;
    const int lrow = lane & 15;
    const int koff = (lane >> 4) * 8;

    U8 ahi[4][4], alo[4][4];
    #pragma unroll
    for (int tt = 0; tt < 4; ++tt) {
        const int tile = t0 + tt;
        if (tile < NTILES) {
            const int row = tile * 16 + lrow;
            #pragma unroll
            for (int ks = 0; ks < 4; ++ks) {
                const float* p = h + (size_t)row * D + ks * 32 + koff;
                float f[8];
                *(f32x4*)&f[0] = *(const f32x4*)p;
                *(f32x4*)&f[4] = *(const f32x4*)(p + 4);
                #pragma unroll
                for (int q = 0; q < 8; ++q) {
                    __bf16 hi = (__bf16)f[q];
                    ahi[tt][ks].e[q] = hi;
                    alo[tt][ks].e[q] = (__bf16)(f[q] - (float)hi);
                }
            }
        } else {
            #pragma unroll
            for (int ks = 0; ks < 4; ++ks) {
                #pragma unroll
                for (int q = 0; q < 8; ++q) {
                    ahi[tt][ks].e[q] = (__bf16)0.f;
                    alo[tt][ks].e[q] = (__bf16)0.f;
                }
            }
        }
    }

    const int jcol = lane & 15;
    const int r0 = (lane >> 4) * 4;

    for (int jt = 0; jt < 8; ++jt) {
        f32x4 accS[4], accN[4];
        #pragma unroll
        for (int tt = 0; tt < 4; ++tt) {
            accS[tt] = (f32x4){0.f, 0.f, 0.f, 0.f};
            accN[tt] = (f32x4){0.f, 0.f, 0.f, 0.f};
        }
        #pragma unroll
        for (int ks = 0; ks < 4; ++ks) {
            const size_t off = (((size_t)jt * 4 + ks) * 64 + lane) * 8;
            const bf16x8 wsh = *(const bf16x8*)(Bs + off);
            const bf16x8 wsl = *(const bf16x8*)(Bs + 16384 + off);
            const bf16x8 wnh = *(const bf16x8*)(Bn + off);
            const bf16x8 wnl = *(const bf16x8*)(Bn + 16384 + off);
            #pragma unroll
            for (int tt = 0; tt < 4; ++tt) {
                accS[tt] = __builtin_amdgcn_mfma_f32_16x16x32_bf16(ahi[tt][ks].v, wsh, accS[tt], 0, 0, 0);
                accS[tt] = __builtin_amdgcn_mfma_f32_16x16x32_bf16(alo[tt][ks].v, wsh, accS[tt], 0, 0, 0);
                accS[tt] = __builtin_amdgcn_mfma_f32_16x16x32_bf16(ahi[tt][ks].v, wsl, accS[tt], 0, 0, 0);
                accN[tt] = __builtin_amdgcn_mfma_f32_16x16x32_bf16(ahi[tt][ks].v, wnh, accN[tt], 0, 0, 0);
                accN[tt] = __builtin_amdgcn_mfma_f32_16x16x32_bf16(alo[tt][ks].v, wnh, accN[tt], 0, 0, 0);
                accN[tt] = __builtin_amdgcn_mfma_f32_16x16x32_bf16(ahi[tt][ks].v, wnl, accN[tt], 0, 0, 0);
            }
        }
        const int j = jt * 16 + jcol;
        const float bj = bias[j];
        #pragma unroll
        for (int tt = 0; tt < 4; ++tt) {
            const int tile = t0 + tt;
            if (tile < NTILES) {
                #pragma unroll
                for (int r = 0; r < 4; ++r) {
                    const size_t n = (size_t)tile * 16 + r0 + r;
                    y_self[n * D + j] = accS[tt][r] + bj;
                    z[n * D + j] = (__bf16)accN[tt][r];
                }
            }
        }
    }
}

// ---------------- aggregate z (bf16) + add y_self (+relu) ----------------
// R5 structure verbatim: one wave per node; 4 edge slots x 16 lanes x 16B
// chunks of the 256B row; wave-uniform trip counts; 16 loads in flight.
__global__ __launch_bounds__(256) void agg_add(
        const __bf16* __restrict__ z, const int* __restrict__ esrc,
        const int* __restrict__ tp, const float* __restrict__ inv_deg,
        const float* __restrict__ y_self, float* __restrict__ out, int do_relu) {
    const int n = blockIdx.x * 4 + (threadIdx.x >> 6);
    const int lane = threadIdx.x & 63;
    const int s = lane >> 4;
    const int c = lane & 15;
    const int r0 = tp[n * NT], r1 = tp[(n + 1) * NT];

    float acc[8] = {0.f, 0.f, 0.f, 0.f, 0.f, 0.f, 0.f, 0.f};
    int e = r0 + s;
    for (; e + 12 < r1; e += 16) {
        int i0 = esrc[e], i1 = esrc[e + 4], i2 = esrc[e + 8], i3 = esrc[e + 12];
        U8 v0, v1, v2, v3;
        v0.v = *(const bf16x8*)(z + (size_t)i0 * D + c * 8);
        v1.v = *(const bf16x8*)(z + (size_t)i1 * D + c * 8);
        v2.v = *(const bf16x8*)(z + (size_t)i2 * D + c * 8);
        v3.v = *(const bf16x8*)(z + (size_t)i3 * D + c * 8);
        #pragma unroll
        for (int t = 0; t < 8; ++t)
            acc[t] += ((float)v0.e[t] + (float)v1.e[t]) + ((float)v2.e[t] + (float)v3.e[t]);
    }
    for (; e < r1; e += 4) {
        U8 v0;
        v0.v = *(const bf16x8*)(z + (size_t)esrc[e] * D + c * 8);
        #pragma unroll
        for (int t = 0; t < 8; ++t) acc[t] += (float)v0.e[t];
    }
    #pragma unroll
    for (int t = 0; t < 8; ++t) acc[t] += __shfl_down(acc[t], 32, 64);
    #pragma unroll
    for (int t = 0; t < 8; ++t) acc[t] += __shfl_down(acc[t], 16, 64);

    if (lane < 16) {
        const float idg = inv_deg[n];
        const float* yp = y_self + (size_t)n * D + c * 8;
        f32x4 y0 = *(const f32x4*)yp;
        f32x4 y1 = *(const f32x4*)(yp + 4);
        float o[8];
        #pragma unroll
        for (int t = 0; t < 4; ++t) o[t] = y0[t] + acc[t] * idg;
        #pragma unroll
        for (int t = 0; t < 4; ++t) o[4 + t] = y1[t] + acc[4 + t] * idg;
        if (do_relu) {
            #pragma unroll
            for (int t = 0; t < 8; ++t) o[t] = fmaxf(o[t], 0.f);
        }
        float* op = out + (size_t)n * D + c * 8;
        *(f32x4*)op = *(f32x4*)&o[0];
        *(f32x4*)(op + 4) = *(f32x4*)&o[4];
    }
}

extern "C" void kernel_launch(void* const* d_in, const int* in_sizes, int n_in,
                              void* d_out, int out_size, void* d_ws, size_t ws_size,
                              hipStream_t stream) {
    const float* x   = (const float*)d_in[0];
    const int* src   = (const int*)d_in[1];
    const int* dst   = (const int*)d_in[2];
    const float* Wn1 = (const float*)d_in[3];
    const float* Ws1 = (const float*)d_in[4];
    const float* b1  = (const float*)d_in[5];
    const float* Wn2 = (const float*)d_in[6];
    const float* Ws2 = (const float*)d_in[7];
    const float* b2  = (const float*)d_in[8];
    const float* Wn3 = (const float*)d_in[9];
    const float* Ws3 = (const float*)d_in[10];
    const float* b3  = (const float*)d_in[11];
    float* out = (float*)d_out;

    char* w = (char*)d_ws;
    float* inv_deg     = (float*)w;             w += 50176 * 4;
    int* tp            = (int*)w;               w += (size_t)NBUCK * 1024 * 4;  // per-(node,tile)
    int* gcursor       = (int*)w;               w += NBUCK * GC_STRIDE * 4;
    int* bucket_base   = (int*)w;               w += 512 * 4;
    int* esrc          = (int*)w;               w += (size_t)N_EDGES * 4;
    __bf16* Bpk        = (__bf16*)w;            w += 6 * 32768 * 2;
    __bf16* zbuf       = (__bf16*)w;            w += (size_t)50176 * D * 2;
    float* bufA        = (float*)w;             // N*D floats

    // bucketbuf (392*6144*4B = 9.63MB) aliases zbuf (12.8MB): consumed by
    // bucket_csr before dual_gemm first writes zbuf (stream-ordered).
    int* bucketbuf = (int*)zbuf;

    const __bf16* PWs1 = Bpk + 0 * 32768, *PWn1 = Bpk + 1 * 32768;
    const __bf16* PWs2 = Bpk + 2 * 32768, *PWn2 = Bpk + 3 * 32768;
    const __bf16* PWs3 = Bpk + 4 * 32768, *PWn3 = Bpk + 5 * 32768;

    // ---- CSR build (bucketed, tile-sorted) ----
    zero1<<<(NBUCK * GC_STRIDE + 255) / 256, 256, 0, stream>>>(gcursor, NBUCK * GC_STRIDE);
    bucket_count_scatter<<<CS_BLOCKS, 256, 0, stream>>>(dst, src, gcursor, bucketbuf);
    bucket_scan<<<1, 512, 0, stream>>>(gcursor, bucket_base);
    bucket_csr<<<NBUCK, 256, 0, stream>>>(gcursor, bucket_base, bucketbuf,
                                          tp, inv_deg, esrc);

    // ---- pack weights (order: Ws1,Wn1,Ws2,Wn2,Ws3,Wn3) ----
    pack_w<<<dim3(64, 6), 256, 0, stream>>>(Ws1, Wn1, Ws2, Wn2, Ws3, Wn3, Bpk);

    const int ggrid = (NTILES + 15) / 16;       // 196 blocks x 4 waves x 4 tiles
    const int agrid = N_NODES / 4;              // 12500 blocks x 4 waves

    // layer 1: h=x -> bufA (relu)
    dual_gemm<<<ggrid, 256, 0, stream>>>(x, PWs1, PWn1, b1, bufA, zbuf);
    agg_add<<<agrid, 256, 0, stream>>>(zbuf, esrc, tp, inv_deg, bufA, bufA, 1);

    // layer 2: h=bufA -> d_out (relu)
    dual_gemm<<<ggrid, 256, 0, stream>>>(bufA, PWs2, PWn2, b2, out, zbuf);
    agg_add<<<agrid, 256, 0, stream>>>(zbuf, esrc, tp, inv_deg, out, out, 1);

    // layer 3: h=d_out -> d_out (no relu), y_self staged in bufA
    dual_gemm<<<ggrid, 256, 0, stream>>>(out, PWs3, PWn3, b3, bufA, zbuf);
    agg_add<<<agrid, 256, 0, stream>>>(zbuf, esrc, tp, inv_deg, bufA, out, 0);
}